// Round 9
// baseline (110.251 us; speedup 1.0000x reference)
//
#include <hip/hip_runtime.h>
#include <hip/hip_bf16.h>
#include <math.h>

// Loss_26886495273741: uniformity loss
//   dots = F F^T (diag masked), I = argmax_row(dots), d = ||F - F[I] + eps||_2
//   loss = -mean(log(n*d))
// F: [16384, 256] fp32.
//
// Round 9: fp8 symmetric MFMA + counted-vmcnt pipeline (T4).
//   4-slot B ring (K=32 slices, 4 KB each), prefetch distance 3,
//   raw s_barrier + s_waitcnt vmcnt(2) (tail 1/0) -- loads stay in flight
//   across barriers; no sched_barrier, no af-persist (lean VGPR).
//   A panel [k16][row][16B] resident in LDS (32 KB). LDS = 49 KB -> 3 blk/CU.
//   B-side fold -> LDS cmb -> plain scratch store (no zeroing, no atomics).
//   Balanced rs remap so concurrent blocks have ~equal triangle spans.
//   A-side fold + packed u64 atomicMax as before. Exact fp32 distances in K2.

#define NROWS 16384
#define DIM   256
#define EPSF  1e-6f

typedef __attribute__((ext_vector_type(4))) float f32x4;

typedef const __attribute__((address_space(1))) void* gas1_t;
typedef __attribute__((address_space(3))) void* las3_t;

__device__ __forceinline__ void glds16(const void* g, void* l) {
    __builtin_amdgcn_global_load_lds((gas1_t)g, (las3_t)l, 16, 0, 0);
}

__device__ __forceinline__ unsigned umax2(unsigned a, unsigned b) {
    return a > b ? a : b;
}

// RNE fp32 -> OCP e4m3fn (subnormal cutoff at 2^-6; codes 0..8 continuous)
__device__ __forceinline__ unsigned f2e4m3(float f) {
    union { float f; unsigned u; } x; x.f = f;
    const unsigned s = (x.u >> 24) & 0x80u;
    const unsigned au = x.u & 0x7FFFFFFFu;
    const float af = __uint_as_float(au);
    if (au < 0x3C800000u) {                    // |x| < 2^-6: subnormal region
        const int q = (int)(af * 512.0f + 0.5f);   // LSB = 2^-9, q in 0..8
        return s | (unsigned)q;
    }
    const unsigned add = 0x7FFFFu + ((au >> 20) & 1u);
    const unsigned v = au + add;
    const unsigned e = (v >> 23) - 120u;       // e4m3 exponent (bias 7), e>=1
    return s | (e << 3) | ((v >> 20) & 7u);
}

// -------- K0: convert fp32 -> fp8 e4m3, zero packed --------
__global__ __launch_bounds__(256)
void convert_kernel(const float* __restrict__ F, unsigned char* __restrict__ F8,
                    unsigned long long* __restrict__ packed)
{
    const int t = blockIdx.x * 256 + threadIdx.x;     // 524288 threads
    const float4 a = *reinterpret_cast<const float4*>(F + (size_t)t * 8);
    const float4 b = *reinterpret_cast<const float4*>(F + (size_t)t * 8 + 4);
    const unsigned lo = f2e4m3(a.x) | (f2e4m3(a.y) << 8) |
                        (f2e4m3(a.z) << 16) | (f2e4m3(a.w) << 24);
    const unsigned hi = f2e4m3(b.x) | (f2e4m3(b.y) << 8) |
                        (f2e4m3(b.z) << 16) | (f2e4m3(b.w) << 24);
    uint2 v; v.x = lo; v.y = hi;
    *reinterpret_cast<uint2*>(F8 + (size_t)t * 8) = v;
    if (t < NROWS) packed[t] = 0ull;
}

// -------- K1: symmetric fp8 MFMA, counted-vmcnt ring pipeline --------
__global__ __launch_bounds__(256, 3)
void mfma_sym_fp8_pipe(const unsigned char* __restrict__ F8,
                       unsigned long long* __restrict__ packed,
                       unsigned long long* __restrict__ scratch)
{
    __shared__ __align__(16) unsigned char As[32768];   // [k16 0..15][row][16B]
    __shared__ __align__(16) unsigned char Bs[16384];   // 4 slots x [k16 0..1][col][16B]
    __shared__ unsigned cmb[256];                       // [rowhalf][col]

    const int tid = threadIdx.x;
    const int w   = tid >> 6;
    const int l   = tid & 63;

    // balanced remap: CU's 4 resident generations get complementary spans
    const int bid  = (int)blockIdx.x;
    const int kgen = bid >> 8;            // 0..3
    const int m5   = (bid >> 3) & 31;     // 0..31
    const int ck   = bid & 7;             // chunk-of-stripe
    const int rs   = (kgen == 0) ? m5 :
                     (kgen == 1) ? 63 - m5 :
                     (kgen == 2) ? 64 + m5 : 127 - m5;
    const int span = 128 - rs;
    const int t0   = rs + ((span * ck) >> 3);
    const int t1   = rs + ((span * (ck + 1)) >> 3);
    if (t0 >= t1) return;                 // block-uniform

    const int row0 = rs * 128;
    const int wrow = (w >> 1) * 64;
    const int wcol = (w & 1) * 64;
    const int lc   = l & 15;
    const int lr4  = l >> 4;
    const int k16r = lr4 >> 1;
    const int odd  = lr4 & 1;

    // ---- prologue: stage A panel (8 glds/wave) then B slices 0..2 (1 each) ----
    #pragma unroll
    for (int m = 0; m < 8; ++m) {
        const int q = 8 * w + m;
        glds16(F8 + (size_t)(row0 + (q & 1) * 64 + l) * DIM + (q >> 1) * 16,
               &As[q * 1024]);
    }
    #pragma unroll
    for (int sl = 0; sl < 3; ++sl)
        glds16(F8 + (size_t)(t0 * 128 + (w & 1) * 64 + l) * DIM + sl * 32 + (w >> 1) * 16,
               &Bs[sl * 4096 + w * 1024]);

    const long* __restrict__ Al = reinterpret_cast<const long*>(As);

    f32x4 acc[4][4];
    #pragma unroll
    for (int i = 0; i < 4; ++i)
        #pragma unroll
        for (int j = 0; j < 4; ++j)
            acc[i][j] = (f32x4){512.f, 512.f, 512.f, 512.f};   // monotonic bias

    unsigned best[4][4] = {};

    for (int t = t0; t < t1; ++t) {
        const bool dt   = (t == rs);
        const bool last = (t == t1 - 1);

        #pragma unroll
        for (int q = 0; q < 8; ++q) {     // K=32 phases; slot = q&3
            // counted wait: slice (t,q) landed; keep 2 slices in flight
            if (!last || q < 6)      asm volatile("s_waitcnt vmcnt(2)" ::: "memory");
            else if (q == 6)         asm volatile("s_waitcnt vmcnt(1)" ::: "memory");
            else                     asm volatile("s_waitcnt vmcnt(0)" ::: "memory");
            __builtin_amdgcn_s_barrier();

            // issue slice gp+3 into slot (q+3)&3 (after barrier: prior reads done)
            if (!last || q < 5) {
                const int nt = t + ((q + 3) >> 3);
                const int nq = (q + 3) & 7;
                glds16(F8 + (size_t)(nt * 128 + (w & 1) * 64 + l) * DIM
                           + nq * 32 + (w >> 1) * 16,
                       &Bs[((q + 3) & 3) * 4096 + w * 1024]);
            }

            const long* __restrict__ Bl =
                reinterpret_cast<const long*>(Bs + (q & 3) * 4096);

            long afv[4], bfv[4];
            #pragma unroll
            for (int i = 0; i < 4; ++i)
                afv[i] = Al[(2 * q + k16r) * 256 + (wrow + i * 16 + lc) * 2 + odd];
            #pragma unroll
            for (int j = 0; j < 4; ++j)
                bfv[j] = Bl[k16r * 256 + (wcol + j * 16 + lc) * 2 + odd];
            #pragma unroll
            for (int j = 0; j < 4; ++j)
                #pragma unroll
                for (int i = 0; i < 4; ++i)
                    acc[i][j] = __builtin_amdgcn_mfma_f32_16x16x32_fp8_fp8(
                        afv[i], bfv[j], acc[i][j], 0, 0, 0);
        }

        // ---- fold: shared masked-bits feed both A-side and B-side keys ----
        const int tl = t - t0;
        unsigned cbA[4];
        #pragma unroll
        for (int j = 0; j < 4; ++j)
            cbA[j] = 2047u - (unsigned)(tl * 128 + wcol + j * 16 + lc);

        #pragma unroll
        for (int j = 0; j < 4; ++j) {
            unsigned kb = 0u;
            #pragma unroll
            for (int i = 0; i < 4; ++i)
                #pragma unroll
                for (int g = 0; g < 4; ++g) {
                    const int r_loc = wrow + i * 16 + lr4 * 4 + g;
                    unsigned m = __float_as_uint(acc[i][j][g]) & 0xFFFFF800u;
                    if (dt && (wcol + j * 16 + lc == r_loc)) m = 0u;
                    best[i][g] = umax2(best[i][g], m | cbA[j]);
                    kb = umax2(kb, m | (unsigned)(127 - r_loc));
                    acc[i][j][g] = 512.f;
                }
            kb = umax2(kb, (unsigned)__shfl_xor((int)kb, 16));
            kb = umax2(kb, (unsigned)__shfl_xor((int)kb, 32));
            if (lr4 == 0) cmb[(w >> 1) * 128 + wcol + j * 16 + lc] = kb;
        }
        asm volatile("s_waitcnt lgkmcnt(0)" ::: "memory");
        __builtin_amdgcn_s_barrier();
        if (w < 2) {                       // plain store: no zeroing, no atomics
            const int c = w * 64 + l;
            const unsigned km = umax2(cmb[c], cmb[128 + c]);
            const unsigned grow = (unsigned)row0 + (127u - (km & 0x7FFu));
            scratch[((size_t)t * 128 + rs) * 128 + c] =
                ((unsigned long long)(km & 0xFFFFF800u) << 32) |
                (0xFFFFFFFFu - grow);
        }
        // next tile's cmb rewrite is separated by its phase-0 barrier
    }

    // ---- A-side: reduce over 16-lane col group, one u64 atomic per row ----
    #pragma unroll
    for (int i = 0; i < 4; ++i)
        #pragma unroll
        for (int g = 0; g < 4; ++g) {
            unsigned key = best[i][g];
            #pragma unroll
            for (int m = 8; m >= 1; m >>= 1)
                key = umax2(key, (unsigned)__shfl_xor((int)key, m));
            if (lc == 0) {
                const int r = row0 + wrow + i * 16 + lr4 * 4 + g;
                const unsigned c = (unsigned)(t0 * 128) + (2047u - (key & 0x7FFu));
                atomicMax(&packed[r],
                          ((unsigned long long)(key & 0xFFFFF800u) << 32) |
                          (0xFFFFFFFFu - c));
            }
        }
}

// ------- K2: merge two-sided candidates + exact fp32 distances + log -------
__global__ __launch_bounds__(256)
void dist_loss_kernel(const float* __restrict__ F,
                      const unsigned long long* __restrict__ packed,
                      const unsigned long long* __restrict__ scratch,
                      double* __restrict__ partials)
{
    const int tid  = threadIdx.x;
    const int lane = tid & 63;
    const int w    = tid >> 6;
    const int gw   = blockIdx.x * 4 + w;       // 1024 waves
    double local = 0.0;
    for (int r = gw; r < NROWS; r += 1024) {
        const int tR = r >> 7;
        const int cl = r & 127;
        unsigned long long best = packed[r];
        const unsigned long long* base = scratch + (size_t)tR * 16384 + cl;
        if (lane <= tR) {
            unsigned long long v = base[(size_t)lane * 128];
            if (lane + 64 <= tR) {
                const unsigned long long v2 = base[(size_t)(lane + 64) * 128];
                if (v2 > v) v = v2;
            }
            if (v > best) best = v;
        }
        #pragma unroll
        for (int m = 32; m >= 1; m >>= 1) {
            const unsigned long long o = __shfl_xor(best, m);
            if (o > best) best = o;
        }
        const int idx = (int)(0xFFFFFFFFu - (unsigned)(best & 0xFFFFFFFFull));

        const float4 a = *reinterpret_cast<const float4*>(
            F + (size_t)r * DIM + (lane << 2));
        const float4 b = *reinterpret_cast<const float4*>(
            F + (size_t)idx * DIM + (lane << 2));
        const float dx = a.x - b.x + EPSF;
        const float dy = a.y - b.y + EPSF;
        const float dz = a.z - b.z + EPSF;
        const float dw = a.w - b.w + EPSF;
        float ss = dx * dx + dy * dy + dz * dz + dw * dw;
        #pragma unroll
        for (int m = 32; m >= 1; m >>= 1) ss += __shfl_xor(ss, m);
        if (lane == 0)
            local += 0.5 * log((double)ss) + log((double)NROWS);
    }
    __shared__ double sm[4];
    if (lane == 0) sm[w] = local;
    __syncthreads();
    if (tid == 0) partials[blockIdx.x] = sm[0] + sm[1] + sm[2] + sm[3];
}

__global__ __launch_bounds__(256)
void finalize_kernel(const double* __restrict__ partials, float* __restrict__ out)
{
    const int tid = threadIdx.x;
    double v = partials[tid];
    #pragma unroll
    for (int m = 32; m >= 1; m >>= 1) v += __shfl_xor(v, m);
    __shared__ double sm[4];
    if ((tid & 63) == 0) sm[tid >> 6] = v;
    __syncthreads();
    if (tid == 0) out[0] = (float)(-(sm[0] + sm[1] + sm[2] + sm[3]) / (double)NROWS);
}

extern "C" void kernel_launch(void* const* d_in, const int* in_sizes, int n_in,
                              void* d_out, int out_size, void* d_ws, size_t ws_size,
                              hipStream_t stream)
{
    const float* F   = (const float*)d_in[0];
    float*       out = (float*)d_out;

    char* ws = (char*)d_ws;
    unsigned char*      F8       = (unsigned char*)ws;                   // 4 MB
    unsigned long long* packed   = (unsigned long long*)(ws + 4194304);  // 128 KB
    unsigned long long* scratch  = (unsigned long long*)(ws + 4325376);  // 16 MB
    double*             partials = (double*)(ws + 21102592);             // 2 KB

    convert_kernel<<<2048, 256, 0, stream>>>(F, F8, packed);
    mfma_sym_fp8_pipe<<<1024, 256, 0, stream>>>(F8, packed, scratch);
    dist_loss_kernel<<<256, 256, 0, stream>>>(F, packed, scratch, partials);
    finalize_kernel<<<1, 256, 0, stream>>>(partials, out);
}